// Round 1
// baseline (602.915 us; speedup 1.0000x reference)
//
#include <hip/hip_runtime.h>
#include <hip/hip_bf16.h>

static constexpr int Hh = 56, Wd = 56, HWsz = 3136;
static constexpr float EPS = 1e-5f;

// ---------------------------------------------------------------------------
// K1: conv1 (1x1, 256->64) + BN1 + ReLU -> out1
//     + fused dynamic-weight branch: 64->16 (BN+ReLU) -> 196 (+bias) -> winv
// one thread per pixel, 64 fp32 accumulators, scalar weight loads
// ---------------------------------------------------------------------------
__global__ __launch_bounds__(64) void k1_conv1_branch(
    const float* __restrict__ x,
    const float* __restrict__ w1,
    const float* __restrict__ bn1g, const float* __restrict__ bn1b,
    const float* __restrict__ bn1m, const float* __restrict__ bn1v,
    const float* __restrict__ c1w,
    const float* __restrict__ ibg, const float* __restrict__ ibb,
    const float* __restrict__ ibm, const float* __restrict__ ibv,
    const float* __restrict__ c2w, const float* __restrict__ c2b,
    float* __restrict__ out1, float* __restrict__ winv)
{
    const int pix = blockIdx.x * 64 + threadIdx.x;
    const int b = pix / HWsz;
    const int hw = pix - b * HWsz;
    const float* xp = x + (size_t)b * 256 * HWsz + hw;

    float acc[64];
#pragma unroll
    for (int o = 0; o < 64; ++o) acc[o] = 0.f;

#pragma unroll 8
    for (int c = 0; c < 256; ++c) {
        const float xv = xp[(size_t)c * HWsz];
#pragma unroll
        for (int o = 0; o < 64; ++o)
            acc[o] = fmaf(w1[o * 256 + c], xv, acc[o]);
    }

    // BN1 + ReLU
#pragma unroll
    for (int o = 0; o < 64; ++o) {
        const float s = bn1g[o] * rsqrtf(bn1v[o] + EPS);
        acc[o] = fmaxf(fmaf(acc[o], s, bn1b[o] - bn1m[o] * s), 0.f);
    }

    float* o1p = out1 + (size_t)b * 64 * HWsz + hw;
#pragma unroll
    for (int o = 0; o < 64; ++o) o1p[(size_t)o * HWsz] = acc[o];

    // branch: t = relu(bn(inv_c1_w @ out1_pix))
    float t[16];
#pragma unroll
    for (int g = 0; g < 16; ++g) {
        float a0 = 0.f, a1 = 0.f, a2 = 0.f, a3 = 0.f;
#pragma unroll
        for (int c = 0; c < 64; c += 4) {
            a0 = fmaf(c1w[g * 64 + c + 0], acc[c + 0], a0);
            a1 = fmaf(c1w[g * 64 + c + 1], acc[c + 1], a1);
            a2 = fmaf(c1w[g * 64 + c + 2], acc[c + 2], a2);
            a3 = fmaf(c1w[g * 64 + c + 3], acc[c + 3], a3);
        }
        const float s = ibg[g] * rsqrtf(ibv[g] + EPS);
        t[g] = fmaxf(fmaf((a0 + a1) + (a2 + a3), s, ibb[g] - ibm[g] * s), 0.f);
    }

    // winv[j] = inv_c2_w[j,:] @ t + inv_c2_b[j]
    float* wp = winv + (size_t)b * 196 * HWsz + hw;
#pragma unroll 2
    for (int j = 0; j < 196; ++j) {
        float a0 = c2b[j], a1 = 0.f, a2 = 0.f, a3 = 0.f;
#pragma unroll
        for (int q = 0; q < 16; q += 4) {
            a0 = fmaf(c2w[j * 16 + q + 0], t[q + 0], a0);
            a1 = fmaf(c2w[j * 16 + q + 1], t[q + 1], a1);
            a2 = fmaf(c2w[j * 16 + q + 2], t[q + 2], a2);
            a3 = fmaf(c2w[j * 16 + q + 3], t[q + 3], a3);
        }
        wp[(size_t)j * HWsz] = (a0 + a1) + (a2 + a3);
    }
}

// ---------------------------------------------------------------------------
// K2: involution (K=7, pad=3) + BN2 + ReLU
// grid (4 row-tiles, 64 b*g), block 448. 2 pixels/thread (aligned ds_read_b64
// windows), 16-channel group staged in LDS in two 8-channel passes.
// ---------------------------------------------------------------------------
__global__ __launch_bounds__(448) void k2_involution(
    const float* __restrict__ out1, const float* __restrict__ winv,
    const float* __restrict__ bn2g, const float* __restrict__ bn2b,
    const float* __restrict__ bn2m, const float* __restrict__ bn2v,
    float* __restrict__ out2)
{
    __shared__ float lds[8 * 22 * 62];   // 43.6 KB: 8 ch x (16+6) rows x (56+6) cols
    const int r0 = blockIdx.x * 16;
    const int bg = blockIdx.y;
    const int b = bg >> 2, g = bg & 3;

    const int row = threadIdx.x / 28;          // 0..15 tile row
    const int txw = threadIdx.x - row * 28;    // 0..27
    const int cb  = 2 * txw;                   // local col of first pixel
    const bool ok = (r0 + row) < Hh;
    const int hw  = (r0 + row) * Wd + cb;

    float2 wreg[49];
    if (ok) {
        const float* wp = winv + ((size_t)b * 196 + (size_t)g * 49) * HWsz + hw;
#pragma unroll
        for (int k = 0; k < 49; ++k)
            wreg[k] = *(const float2*)(wp + (size_t)k * HWsz);
    }

    float accA[16], accB[16];
#pragma unroll
    for (int c = 0; c < 16; ++c) { accA[c] = 0.f; accB[c] = 0.f; }

#pragma unroll
    for (int pass = 0; pass < 2; ++pass) {
        __syncthreads();
        const float* src = out1 + ((size_t)b * 64 + g * 16 + pass * 8) * HWsz;
        for (int li = threadIdx.x; li < 8 * 22 * 62; li += 448) {
            const int c  = li / (22 * 62);
            int rem      = li - c * (22 * 62);
            const int rr = rem / 62;
            const int cc = rem - rr * 62;
            const int gr = r0 + rr - 3;
            const int gc = cc - 3;
            float v = 0.f;
            if (gr >= 0 && gr < Hh && gc >= 0 && gc < Wd)
                v = src[(size_t)c * HWsz + gr * Wd + gc];
            lds[li] = v;
        }
        __syncthreads();

        if (ok) {
#pragma unroll
            for (int c8 = 0; c8 < 8; ++c8) {
#pragma unroll
                for (int kh = 0; kh < 7; ++kh) {
                    const float* lrow = &lds[(c8 * 22 + row + kh) * 62 + cb];
                    float win[8];
                    *(float2*)&win[0] = *(const float2*)(lrow + 0);
                    *(float2*)&win[2] = *(const float2*)(lrow + 2);
                    *(float2*)&win[4] = *(const float2*)(lrow + 4);
                    *(float2*)&win[6] = *(const float2*)(lrow + 6);
#pragma unroll
                    for (int kw = 0; kw < 7; ++kw) {
                        const float2 wk = wreg[kh * 7 + kw];
                        const int ci = pass * 8 + c8;
                        accA[ci] = fmaf(wk.x, win[kw], accA[ci]);
                        accB[ci] = fmaf(wk.y, win[kw + 1], accB[ci]);
                    }
                }
            }
        }
    }

    if (ok) {
        float* op = out2 + ((size_t)b * 64 + g * 16) * HWsz + hw;
#pragma unroll
        for (int i = 0; i < 16; ++i) {
            const int ch = g * 16 + i;
            const float s   = bn2g[ch] * rsqrtf(bn2v[ch] + EPS);
            const float off = bn2b[ch] - bn2m[ch] * s;
            float2 v;
            v.x = fmaxf(fmaf(accA[i], s, off), 0.f);
            v.y = fmaxf(fmaf(accB[i], s, off), 0.f);
            *(float2*)(op + (size_t)i * HWsz) = v;
        }
    }
}

// ---------------------------------------------------------------------------
// K3: conv3 (1x1, 64->256) + BN3 + residual + ReLU
// one thread per pixel holds 64 input channels; 128 outputs per block
// ---------------------------------------------------------------------------
__global__ __launch_bounds__(64) void k3_conv3(
    const float* __restrict__ out2, const float* __restrict__ x,
    const float* __restrict__ w3,
    const float* __restrict__ bn3g, const float* __restrict__ bn3b,
    const float* __restrict__ bn3m, const float* __restrict__ bn3v,
    float* __restrict__ out)
{
    const int pix = blockIdx.x * 64 + threadIdx.x;
    const int b = pix / HWsz;
    const int hw = pix - b * HWsz;
    const int obase = blockIdx.y * 128;

    const float* ip = out2 + (size_t)b * 64 * HWsz + hw;
    float v[64];
#pragma unroll 8
    for (int c = 0; c < 64; ++c) v[c] = ip[(size_t)c * HWsz];

    const float* xp = x + ((size_t)b * 256 + obase) * HWsz + hw;
    float* op = out + ((size_t)b * 256 + obase) * HWsz + hw;

#pragma unroll 2
    for (int oo = 0; oo < 128; ++oo) {
        const int o = obase + oo;
        const float* wr = w3 + o * 64;
        float a0 = 0.f, a1 = 0.f, a2 = 0.f, a3 = 0.f;
#pragma unroll
        for (int c = 0; c < 64; c += 4) {
            a0 = fmaf(wr[c + 0], v[c + 0], a0);
            a1 = fmaf(wr[c + 1], v[c + 1], a1);
            a2 = fmaf(wr[c + 2], v[c + 2], a2);
            a3 = fmaf(wr[c + 3], v[c + 3], a3);
        }
        const float s   = bn3g[o] * rsqrtf(bn3v[o] + EPS);
        const float off = bn3b[o] - bn3m[o] * s;
        const float val = fmaf((a0 + a1) + (a2 + a3), s, off) + xp[(size_t)oo * HWsz];
        op[(size_t)oo * HWsz] = fmaxf(val, 0.f);
    }
}

extern "C" void kernel_launch(void* const* d_in, const int* in_sizes, int n_in,
                              void* d_out, int out_size, void* d_ws, size_t ws_size,
                              hipStream_t stream)
{
    const float* x    = (const float*)d_in[0];
    const float* w1   = (const float*)d_in[1];
    const float* bn1g = (const float*)d_in[2];
    const float* bn1b = (const float*)d_in[3];
    const float* bn1m = (const float*)d_in[4];
    const float* bn1v = (const float*)d_in[5];
    const float* c1w  = (const float*)d_in[6];
    const float* ibg  = (const float*)d_in[7];
    const float* ibb  = (const float*)d_in[8];
    const float* ibm  = (const float*)d_in[9];
    const float* ibv  = (const float*)d_in[10];
    const float* c2w  = (const float*)d_in[11];
    const float* c2b  = (const float*)d_in[12];
    const float* bn2g = (const float*)d_in[13];
    const float* bn2b = (const float*)d_in[14];
    const float* bn2m = (const float*)d_in[15];
    const float* bn2v = (const float*)d_in[16];
    const float* w3   = (const float*)d_in[17];
    const float* bn3g = (const float*)d_in[18];
    const float* bn3b = (const float*)d_in[19];
    const float* bn3m = (const float*)d_in[20];
    const float* bn3v = (const float*)d_in[21];

    // ws: out1 [16,64,3136] fp32, out2 [16,64,3136] fp32  (25.7 MB total)
    // winv [16,196,3136] fp32 lives in d_out (dead before K3 writes output)
    float* out1 = (float*)d_ws;
    float* out2 = (float*)d_ws + 3211264;
    float* winv = (float*)d_out;

    k1_conv1_branch<<<dim3(784), dim3(64), 0, stream>>>(
        x, w1, bn1g, bn1b, bn1m, bn1v, c1w, ibg, ibb, ibm, ibv, c2w, c2b,
        out1, winv);

    k2_involution<<<dim3(4, 64), dim3(448), 0, stream>>>(
        out1, winv, bn2g, bn2b, bn2m, bn2v, out2);

    k3_conv3<<<dim3(784, 2), dim3(64), 0, stream>>>(
        out2, x, w3, bn3g, bn3b, bn3m, bn3v, (float*)d_out);
}

// Round 2
// 287.787 us; speedup vs baseline: 2.0950x; 2.0950x over previous
//
#include <hip/hip_runtime.h>
#include <hip/hip_bf16.h>

static constexpr int Hh = 56, Wd = 56, HWsz = 3136;
static constexpr float EPS = 1e-5f;

// ---------------------------------------------------------------------------
// K1: conv1 (1x1, 256->64) + BN1 + ReLU -> out1, fused dynamic-weight branch.
// Block 256 thr = 4 waves. Block tile: 64 pixels x 64 outputs, K chunked by 64
// through LDS (16KB). Thread = 1 pixel x 16 outputs. Wave-uniform weight
// indices via readfirstlane -> s_load. Branch: out1 tile restaged in LDS,
// each wave produces 49 of the 196 winv channels for its pixel.
// ---------------------------------------------------------------------------
__global__ __launch_bounds__(256) void k1_conv1_branch(
    const float* __restrict__ x,
    const float* __restrict__ w1,
    const float* __restrict__ bn1g, const float* __restrict__ bn1b,
    const float* __restrict__ bn1m, const float* __restrict__ bn1v,
    const float* __restrict__ c1w,
    const float* __restrict__ ibg, const float* __restrict__ ibb,
    const float* __restrict__ ibm, const float* __restrict__ ibv,
    const float* __restrict__ c2w, const float* __restrict__ c2b,
    float* __restrict__ out1, float* __restrict__ winv)
{
    __shared__ float lds[64 * 64];           // 16 KB
    const int tid  = threadIdx.x;
    const int lane = tid & 63;
    const int wv   = __builtin_amdgcn_readfirstlane(tid >> 6);   // 0..3, SGPR
    const int pix0 = blockIdx.x * 64;        // 784 blocks; 3136 % 64 == 0 so
    const int b    = pix0 / HWsz;            // a block never crosses a batch
    const int hw0  = pix0 - b * HWsz;
    const float* xb = x + (size_t)b * 256 * HWsz + hw0;

    float acc[16];
#pragma unroll
    for (int i = 0; i < 16; ++i) acc[i] = 0.f;

    for (int c0 = 0; c0 < 256; c0 += 64) {
        __syncthreads();
#pragma unroll
        for (int i = 0; i < 16; ++i) {
            const int ch = wv * 16 + i;
            lds[ch * 64 + lane] = xb[(size_t)(c0 + ch) * HWsz + lane];
        }
        __syncthreads();
        const float* wrow = w1 + wv * 16 * 256 + c0;   // SGPR base
#pragma unroll 8
        for (int c = 0; c < 64; ++c) {
            const float xv = lds[c * 64 + lane];
#pragma unroll
            for (int i = 0; i < 16; ++i)
                acc[i] = fmaf(wrow[i * 256 + c], xv, acc[i]);
        }
    }

    // BN1 + ReLU; write out1 and restage tile into LDS for the branch
    __syncthreads();
    {
        const int o0 = wv * 16;
        float* o1p = out1 + (size_t)b * 64 * HWsz + hw0;
#pragma unroll
        for (int i = 0; i < 16; ++i) {
            const int o = o0 + i;
            const float s = bn1g[o] * rsqrtf(bn1v[o] + EPS);
            const float v = fmaxf(fmaf(acc[i], s, bn1b[o] - bn1m[o] * s), 0.f);
            lds[o * 64 + lane] = v;
            o1p[(size_t)o * HWsz + lane] = v;
        }
    }
    __syncthreads();

    // branch stage 1: t[16] = relu(bn(inv_c1_w @ out1_pix)), c-outer accumulate
    float tg[16];
#pragma unroll
    for (int g = 0; g < 16; ++g) tg[g] = 0.f;
#pragma unroll 8
    for (int c = 0; c < 64; ++c) {
        const float v = lds[c * 64 + lane];
#pragma unroll
        for (int g = 0; g < 16; ++g)
            tg[g] = fmaf(c1w[g * 64 + c], v, tg[g]);
    }
#pragma unroll
    for (int g = 0; g < 16; ++g) {
        const float s = ibg[g] * rsqrtf(ibv[g] + EPS);
        tg[g] = fmaxf(fmaf(tg[g], s, ibb[g] - ibm[g] * s), 0.f);
    }

    // branch stage 2: this wave emits j in [wv*49, wv*49+49)
    const int j0 = wv * 49;
    float* wp = winv + ((size_t)b * 196 + j0) * HWsz + hw0 + lane;
#pragma unroll 7
    for (int jj = 0; jj < 49; ++jj) {
        const int j = j0 + jj;
        float a = c2b[j];
#pragma unroll
        for (int q = 0; q < 16; ++q)
            a = fmaf(c2w[j * 16 + q], tg[q], a);
        wp[(size_t)jj * HWsz] = a;
    }
}

// ---------------------------------------------------------------------------
// K2: involution (K=7, pad=3) + BN2 + ReLU
// grid (4 row-tiles, 64 b*g, 2 channel-halves), block 448 (16 rows x 28,
// 2 px/thread). 8 channels staged in LDS (43.6KB). kh-outer keeps only 7
// float2 weights live -> low VGPR.
// ---------------------------------------------------------------------------
__global__ __launch_bounds__(448) void k2_involution(
    const float* __restrict__ out1, const float* __restrict__ winv,
    const float* __restrict__ bn2g, const float* __restrict__ bn2b,
    const float* __restrict__ bn2m, const float* __restrict__ bn2v,
    float* __restrict__ out2)
{
    __shared__ float lds[8 * 22 * 62];   // 43.6 KB
    const int r0 = blockIdx.x * 16;
    const int b  = blockIdx.y >> 2, g = blockIdx.y & 3;
    const int ch0 = g * 16 + blockIdx.z * 8;     // within-image channel base

    const int row = threadIdx.x / 28;
    const int txw = threadIdx.x - row * 28;
    const int cb  = 2 * txw;
    const bool ok = (r0 + row) < Hh;
    const int hw  = ok ? ((r0 + row) * Wd + cb) : 0;

    const float* src = out1 + ((size_t)b * 64 + ch0) * HWsz;
    for (int li = threadIdx.x; li < 8 * 22 * 62; li += 448) {
        const int c  = li / (22 * 62);
        int rem      = li - c * (22 * 62);
        const int rr = rem / 62;
        const int cc = rem - rr * 62;
        const int gr = r0 + rr - 3;
        const int gc = cc - 3;
        float v = 0.f;
        if (gr >= 0 && gr < Hh && gc >= 0 && gc < Wd)
            v = src[(size_t)c * HWsz + gr * Wd + gc];
        lds[li] = v;
    }
    __syncthreads();

    float2 acc[8];
#pragma unroll
    for (int i = 0; i < 8; ++i) { acc[i].x = 0.f; acc[i].y = 0.f; }

    const float* wp = winv + ((size_t)b * 196 + g * 49) * HWsz + hw;
#pragma unroll
    for (int kh = 0; kh < 7; ++kh) {
        float2 wk[7];
#pragma unroll
        for (int kw = 0; kw < 7; ++kw)
            wk[kw] = *(const float2*)(wp + (size_t)(kh * 7 + kw) * HWsz);
#pragma unroll
        for (int c8 = 0; c8 < 8; ++c8) {
            const float* lrow = &lds[(c8 * 22 + row + kh) * 62 + cb];
            float win[8];
            *(float2*)&win[0] = *(const float2*)(lrow + 0);
            *(float2*)&win[2] = *(const float2*)(lrow + 2);
            *(float2*)&win[4] = *(const float2*)(lrow + 4);
            *(float2*)&win[6] = *(const float2*)(lrow + 6);
#pragma unroll
            for (int kw = 0; kw < 7; ++kw) {
                acc[c8].x = fmaf(wk[kw].x, win[kw], acc[c8].x);
                acc[c8].y = fmaf(wk[kw].y, win[kw + 1], acc[c8].y);
            }
        }
    }

    if (ok) {
        float* op = out2 + ((size_t)b * 64 + ch0) * HWsz + hw;
#pragma unroll
        for (int i = 0; i < 8; ++i) {
            const int ch = ch0 + i;
            const float s   = bn2g[ch] * rsqrtf(bn2v[ch] + EPS);
            const float off = bn2b[ch] - bn2m[ch] * s;
            float2 v;
            v.x = fmaxf(fmaf(acc[i].x, s, off), 0.f);
            v.y = fmaxf(fmaf(acc[i].y, s, off), 0.f);
            *(float2*)(op + (size_t)i * HWsz) = v;
        }
    }
}

// ---------------------------------------------------------------------------
// K3: conv3 (1x1, 64->256) + BN3 + residual + ReLU
// Block 256 thr: 64 pixels x 128 outputs (grid.y=2), out2 tile in LDS,
// thread = 1 pixel x 32 outputs, scalar w3 loads.
// ---------------------------------------------------------------------------
__global__ __launch_bounds__(256) void k3_conv3(
    const float* __restrict__ out2, const float* __restrict__ x,
    const float* __restrict__ w3,
    const float* __restrict__ bn3g, const float* __restrict__ bn3b,
    const float* __restrict__ bn3m, const float* __restrict__ bn3v,
    float* __restrict__ out)
{
    __shared__ float lds[64 * 64];       // 16 KB
    const int tid  = threadIdx.x;
    const int lane = tid & 63;
    const int wv   = __builtin_amdgcn_readfirstlane(tid >> 6);
    const int pix0 = blockIdx.x * 64;
    const int b    = pix0 / HWsz;
    const int hw0  = pix0 - b * HWsz;

    const float* ip = out2 + (size_t)b * 64 * HWsz + hw0;
#pragma unroll
    for (int i = 0; i < 16; ++i) {
        const int ch = wv * 16 + i;
        lds[ch * 64 + lane] = ip[(size_t)ch * HWsz + lane];
    }
    __syncthreads();

    const int o0 = blockIdx.y * 128 + wv * 32;   // SGPR
    float acc[32];
#pragma unroll
    for (int i = 0; i < 32; ++i) acc[i] = 0.f;

    const float* wbase = w3 + o0 * 64;
#pragma unroll 4
    for (int c = 0; c < 64; ++c) {
        const float v = lds[c * 64 + lane];
#pragma unroll
        for (int i = 0; i < 32; ++i)
            acc[i] = fmaf(wbase[i * 64 + c], v, acc[i]);
    }

    const float* xp = x   + ((size_t)b * 256 + o0) * HWsz + hw0 + lane;
    float*       op = out + ((size_t)b * 256 + o0) * HWsz + hw0 + lane;
#pragma unroll 4
    for (int i = 0; i < 32; ++i) {
        const int o = o0 + i;
        const float s   = bn3g[o] * rsqrtf(bn3v[o] + EPS);
        const float off = bn3b[o] - bn3m[o] * s;
        const float val = fmaf(acc[i], s, off) + xp[(size_t)i * HWsz];
        op[(size_t)i * HWsz] = fmaxf(val, 0.f);
    }
}

extern "C" void kernel_launch(void* const* d_in, const int* in_sizes, int n_in,
                              void* d_out, int out_size, void* d_ws, size_t ws_size,
                              hipStream_t stream)
{
    const float* x    = (const float*)d_in[0];
    const float* w1   = (const float*)d_in[1];
    const float* bn1g = (const float*)d_in[2];
    const float* bn1b = (const float*)d_in[3];
    const float* bn1m = (const float*)d_in[4];
    const float* bn1v = (const float*)d_in[5];
    const float* c1w  = (const float*)d_in[6];
    const float* ibg  = (const float*)d_in[7];
    const float* ibb  = (const float*)d_in[8];
    const float* ibm  = (const float*)d_in[9];
    const float* ibv  = (const float*)d_in[10];
    const float* c2w  = (const float*)d_in[11];
    const float* c2b  = (const float*)d_in[12];
    const float* bn2g = (const float*)d_in[13];
    const float* bn2b = (const float*)d_in[14];
    const float* bn2m = (const float*)d_in[15];
    const float* bn2v = (const float*)d_in[16];
    const float* w3   = (const float*)d_in[17];
    const float* bn3g = (const float*)d_in[18];
    const float* bn3b = (const float*)d_in[19];
    const float* bn3m = (const float*)d_in[20];
    const float* bn3v = (const float*)d_in[21];

    // ws: out1 [16,64,3136] fp32, out2 [16,64,3136] fp32 (25.7 MB total)
    // winv [16,196,3136] fp32 lives in d_out (dead before K3 writes output)
    float* out1 = (float*)d_ws;
    float* out2 = (float*)d_ws + 3211264;
    float* winv = (float*)d_out;

    k1_conv1_branch<<<dim3(784), dim3(256), 0, stream>>>(
        x, w1, bn1g, bn1b, bn1m, bn1v, c1w, ibg, ibb, ibm, ibv, c2w, c2b,
        out1, winv);

    k2_involution<<<dim3(4, 64, 2), dim3(448), 0, stream>>>(
        out1, winv, bn2g, bn2b, bn2m, bn2v, out2);

    k3_conv3<<<dim3(784, 2), dim3(256), 0, stream>>>(
        out2, x, w3, bn3g, bn3b, bn3m, bn3v, (float*)d_out);
}

// Round 3
// 250.392 us; speedup vs baseline: 2.4079x; 1.1493x over previous
//
#include <hip/hip_runtime.h>
#include <hip/hip_bf16.h>

static constexpr int Hh = 56, Wd = 56, HWsz = 3136;
static constexpr float EPS = 1e-5f;

// ---------------------------------------------------------------------------
// prep: transpose weights so inner loops read contiguous scalar runs.
//   w1t[c][o]  (256x64)  from w1[o][c]  (64x256)
//   w3t[c][o]  (64x256)  from w3[o][c]  (256x64)
//   c1wt[c][g] (64x16)   from c1w[g][c] (16x64)
// ---------------------------------------------------------------------------
__global__ __launch_bounds__(256) void prep_transpose(
    const float* __restrict__ w1, const float* __restrict__ w3,
    const float* __restrict__ c1w,
    float* __restrict__ w1t, float* __restrict__ w3t, float* __restrict__ c1wt)
{
    const int idx = blockIdx.x * 256 + threadIdx.x;   // grid 64 -> 16384
    {
        const int c = idx >> 6, o = idx & 63;         // w1t[c*64+o]
        w1t[idx] = w1[o * 256 + c];
    }
    {
        const int c = idx >> 8, o = idx & 255;        // w3t[c*256+o]
        w3t[idx] = w3[o * 64 + c];
    }
    if (idx < 1024) {
        const int c = idx >> 4, g = idx & 15;         // c1wt[c*16+g]
        c1wt[idx] = c1w[g * 64 + c];
    }
}

// ---------------------------------------------------------------------------
// K1: conv1 (1x1, 256->64) + BN1 + ReLU -> out1, fused dynamic-weight branch.
// 512 thr = 8 waves; 64 px x 64 out per block; thread = 1 px x 8 outs.
// Weights via contiguous s_load (w1t). Branch: waves 0-1 compute t (16x64 in
// LDS), all 8 waves emit 24-25 of the 196 winv channels.
// ---------------------------------------------------------------------------
__global__ __launch_bounds__(512) void k1_conv1_branch(
    const float* __restrict__ x,
    const float* __restrict__ w1t,
    const float* __restrict__ bn1g, const float* __restrict__ bn1b,
    const float* __restrict__ bn1m, const float* __restrict__ bn1v,
    const float* __restrict__ c1wt,
    const float* __restrict__ ibg, const float* __restrict__ ibb,
    const float* __restrict__ ibm, const float* __restrict__ ibv,
    const float* __restrict__ c2w, const float* __restrict__ c2b,
    float* __restrict__ out1, float* __restrict__ winv)
{
    __shared__ float lds[64 * 64];   // 16 KB: [channel][pixel]
    __shared__ float tls[16 * 64];   // 4 KB:  [g][pixel]
    const int tid  = threadIdx.x;
    const int lane = tid & 63;
    const int wv   = __builtin_amdgcn_readfirstlane(tid >> 6);   // 0..7
    const int pix0 = blockIdx.x * 64;
    const int b    = pix0 / HWsz;
    const int hw0  = pix0 - b * HWsz;
    const float* xb = x + (size_t)b * 256 * HWsz + hw0;

    const int o0 = wv * 8;
    float acc[8];
#pragma unroll
    for (int i = 0; i < 8; ++i) acc[i] = 0.f;

    for (int c0 = 0; c0 < 256; c0 += 64) {
        __syncthreads();
#pragma unroll
        for (int i = 0; i < 8; ++i) {
            const int ch = wv * 8 + i;
            lds[ch * 64 + lane] = xb[(size_t)(c0 + ch) * HWsz + lane];
        }
        __syncthreads();
#pragma unroll 8
        for (int c = 0; c < 64; ++c) {
            const float xv = lds[c * 64 + lane];
            const float* wr = w1t + (c0 + c) * 64 + o0;   // contiguous 8 -> s_load_dwordx8
#pragma unroll
            for (int i = 0; i < 8; ++i)
                acc[i] = fmaf(wr[i], xv, acc[i]);
        }
    }

    // BN1 + ReLU; write out1 and restage tile for the branch
    __syncthreads();
    {
        float* o1p = out1 + (size_t)b * 64 * HWsz + hw0 + lane;
#pragma unroll
        for (int i = 0; i < 8; ++i) {
            const int o = o0 + i;
            const float s = bn1g[o] * rsqrtf(bn1v[o] + EPS);
            const float v = fmaxf(fmaf(acc[i], s, bn1b[o] - bn1m[o] * s), 0.f);
            lds[o * 64 + lane] = v;
            o1p[(size_t)o * HWsz] = v;
        }
    }
    __syncthreads();

    // branch stage 1 (waves 0,1): t[g] = relu(bn(c1w @ out1_pix))
    if (wv < 2) {
        const int g0 = wv * 8;
        float ta[8];
#pragma unroll
        for (int i = 0; i < 8; ++i) ta[i] = 0.f;
#pragma unroll 8
        for (int c = 0; c < 64; ++c) {
            const float v = lds[c * 64 + lane];
            const float* cr = c1wt + c * 16 + g0;         // contiguous 8
#pragma unroll
            for (int i = 0; i < 8; ++i)
                ta[i] = fmaf(cr[i], v, ta[i]);
        }
#pragma unroll
        for (int i = 0; i < 8; ++i) {
            const int g = g0 + i;
            const float s = ibg[g] * rsqrtf(ibv[g] + EPS);
            tls[g * 64 + lane] = fmaxf(fmaf(ta[i], s, ibb[g] - ibm[g] * s), 0.f);
        }
    }
    __syncthreads();

    float tg[16];
#pragma unroll
    for (int q = 0; q < 16; ++q) tg[q] = tls[q * 64 + lane];

    // branch stage 2: wave wv emits jn channels starting at j0
    const int j0 = (wv < 4) ? wv * 25 : 100 + (wv - 4) * 24;
    const int jn = (wv < 4) ? 25 : 24;
    float* wp = winv + ((size_t)b * 196 + j0) * HWsz + hw0 + lane;
    for (int jj = 0; jj < jn; ++jj) {
        const int j = j0 + jj;
        const float* cw = c2w + j * 16;                   // contiguous 16
        float a = c2b[j];
#pragma unroll
        for (int q = 0; q < 16; ++q)
            a = fmaf(cw[q], tg[q], a);
        wp[(size_t)jj * HWsz] = a;
    }
}

// ---------------------------------------------------------------------------
// K2: involution (K=7, pad=3) + BN2 + ReLU
// grid (4 row-tiles, 64 b*g, 2 channel-halves), block 448 (16 rows x 28,
// 2 px/thread). 8 channels staged in LDS, row stride padded to 64 so the
// staging loop is shift/mask only.
// ---------------------------------------------------------------------------
__global__ __launch_bounds__(448) void k2_involution(
    const float* __restrict__ out1, const float* __restrict__ winv,
    const float* __restrict__ bn2g, const float* __restrict__ bn2b,
    const float* __restrict__ bn2m, const float* __restrict__ bn2v,
    float* __restrict__ out2)
{
    __shared__ float lds[8 * 22 * 64];   // 44 KB
    const int r0  = blockIdx.x * 16;
    const int b   = blockIdx.y >> 2, g = blockIdx.y & 3;
    const int ch0 = g * 16 + blockIdx.z * 8;

    const int tid = threadIdx.x;
    const int row = tid / 28;
    const int txw = tid - row * 28;
    const int cb  = 2 * txw;
    const bool ok = (r0 + row) < Hh;
    const int hw  = (r0 + row) * Wd + cb;

    const float* src = out1 + ((size_t)b * 64 + ch0) * HWsz;
#pragma unroll
    for (int c = 0; c < 8; ++c) {
        for (int idx = tid; idx < 22 * 64; idx += 448) {
            const int rr = idx >> 6, cc = idx & 63;
            const int gr = r0 + rr - 3, gc = cc - 3;
            float v = 0.f;
            if (cc < 62 && gr >= 0 && gr < Hh && gc >= 0 && gc < Wd)
                v = src[(size_t)c * HWsz + gr * Wd + gc];
            lds[(c * 22 + rr) * 64 + cc] = v;
        }
    }
    __syncthreads();

    if (ok) {
        float2 acc[8];
#pragma unroll
        for (int i = 0; i < 8; ++i) { acc[i].x = 0.f; acc[i].y = 0.f; }

        const float* wp = winv + ((size_t)b * 196 + g * 49) * HWsz + hw;
#pragma unroll
        for (int kh = 0; kh < 7; ++kh) {
            float2 wk[7];
#pragma unroll
            for (int kw = 0; kw < 7; ++kw)
                wk[kw] = *(const float2*)(wp + (size_t)(kh * 7 + kw) * HWsz);
#pragma unroll
            for (int c8 = 0; c8 < 8; ++c8) {
                const float* lrow = &lds[(c8 * 22 + row + kh) * 64 + cb];
                float win[8];
                *(float2*)&win[0] = *(const float2*)(lrow + 0);
                *(float2*)&win[2] = *(const float2*)(lrow + 2);
                *(float2*)&win[4] = *(const float2*)(lrow + 4);
                *(float2*)&win[6] = *(const float2*)(lrow + 6);
#pragma unroll
                for (int kw = 0; kw < 7; ++kw) {
                    acc[c8].x = fmaf(wk[kw].x, win[kw], acc[c8].x);
                    acc[c8].y = fmaf(wk[kw].y, win[kw + 1], acc[c8].y);
                }
            }
        }

        float* op = out2 + ((size_t)b * 64 + ch0) * HWsz + hw;
#pragma unroll
        for (int i = 0; i < 8; ++i) {
            const int ch = ch0 + i;
            const float s   = bn2g[ch] * rsqrtf(bn2v[ch] + EPS);
            const float off = bn2b[ch] - bn2m[ch] * s;
            float2 v;
            v.x = fmaxf(fmaf(acc[i].x, s, off), 0.f);
            v.y = fmaxf(fmaf(acc[i].y, s, off), 0.f);
            *(float2*)(op + (size_t)i * HWsz) = v;
        }
    }
}

// ---------------------------------------------------------------------------
// K3: conv3 (1x1, 64->256) + BN3 + residual + ReLU
// grid (784,2), 512 thr: 64 px x 128 outs; thread = 1 px x 16 outs;
// contiguous s_load_dwordx16 weights (w3t).
// ---------------------------------------------------------------------------
__global__ __launch_bounds__(512) void k3_conv3(
    const float* __restrict__ out2, const float* __restrict__ x,
    const float* __restrict__ w3t,
    const float* __restrict__ bn3g, const float* __restrict__ bn3b,
    const float* __restrict__ bn3m, const float* __restrict__ bn3v,
    float* __restrict__ out)
{
    __shared__ float lds[64 * 64];   // 16 KB
    const int tid  = threadIdx.x;
    const int lane = tid & 63;
    const int wv   = __builtin_amdgcn_readfirstlane(tid >> 6);   // 0..7
    const int pix0 = blockIdx.x * 64;
    const int b    = pix0 / HWsz;
    const int hw0  = pix0 - b * HWsz;

    const float* ip = out2 + (size_t)b * 64 * HWsz + hw0 + lane;
#pragma unroll
    for (int i = 0; i < 8; ++i) {
        const int ch = wv * 8 + i;
        lds[ch * 64 + lane] = ip[(size_t)ch * HWsz];
    }
    __syncthreads();

    const int o0 = blockIdx.y * 128 + wv * 16;
    float acc[16];
#pragma unroll
    for (int i = 0; i < 16; ++i) acc[i] = 0.f;

#pragma unroll 4
    for (int c = 0; c < 64; ++c) {
        const float v = lds[c * 64 + lane];
        const float* wr = w3t + c * 256 + o0;    // contiguous 16 -> s_load_dwordx16
#pragma unroll
        for (int i = 0; i < 16; ++i)
            acc[i] = fmaf(wr[i], v, acc[i]);
    }

    const float* xp = x   + ((size_t)b * 256 + o0) * HWsz + hw0 + lane;
    float*       op = out + ((size_t)b * 256 + o0) * HWsz + hw0 + lane;
#pragma unroll 4
    for (int i = 0; i < 16; ++i) {
        const int o = o0 + i;
        const float s   = bn3g[o] * rsqrtf(bn3v[o] + EPS);
        const float off = bn3b[o] - bn3m[o] * s;
        const float val = fmaf(acc[i], s, off) + xp[(size_t)i * HWsz];
        op[(size_t)i * HWsz] = fmaxf(val, 0.f);
    }
}

extern "C" void kernel_launch(void* const* d_in, const int* in_sizes, int n_in,
                              void* d_out, int out_size, void* d_ws, size_t ws_size,
                              hipStream_t stream)
{
    const float* x    = (const float*)d_in[0];
    const float* w1   = (const float*)d_in[1];
    const float* bn1g = (const float*)d_in[2];
    const float* bn1b = (const float*)d_in[3];
    const float* bn1m = (const float*)d_in[4];
    const float* bn1v = (const float*)d_in[5];
    const float* c1w  = (const float*)d_in[6];
    const float* ibg  = (const float*)d_in[7];
    const float* ibb  = (const float*)d_in[8];
    const float* ibm  = (const float*)d_in[9];
    const float* ibv  = (const float*)d_in[10];
    const float* c2w  = (const float*)d_in[11];
    const float* c2b  = (const float*)d_in[12];
    const float* bn2g = (const float*)d_in[13];
    const float* bn2b = (const float*)d_in[14];
    const float* bn2m = (const float*)d_in[15];
    const float* bn2v = (const float*)d_in[16];
    const float* w3   = (const float*)d_in[17];
    const float* bn3g = (const float*)d_in[18];
    const float* bn3b = (const float*)d_in[19];
    const float* bn3m = (const float*)d_in[20];
    const float* bn3v = (const float*)d_in[21];

    // ws layout (floats): out1 [0, 3211264) | out2 [.., 6422528)
    //                     w1t 16384 | w3t 16384 | c1wt 1024
    float* out1 = (float*)d_ws;
    float* out2 = (float*)d_ws + 3211264;
    float* w1t  = (float*)d_ws + 6422528;
    float* w3t  = w1t + 16384;
    float* c1wt = w3t + 16384;
    float* winv = (float*)d_out;   // dead before k3 writes the real output

    prep_transpose<<<dim3(64), dim3(256), 0, stream>>>(w1, w3, c1w, w1t, w3t, c1wt);

    k1_conv1_branch<<<dim3(784), dim3(512), 0, stream>>>(
        x, w1t, bn1g, bn1b, bn1m, bn1v, c1wt, ibg, ibb, ibm, ibv, c2w, c2b,
        out1, winv);

    k2_involution<<<dim3(4, 64, 2), dim3(448), 0, stream>>>(
        out1, winv, bn2g, bn2b, bn2m, bn2v, out2);

    k3_conv3<<<dim3(784, 2), dim3(512), 0, stream>>>(
        out2, x, w3t, bn3g, bn3b, bn3m, bn3v, (float*)d_out);
}